// Round 9
// baseline (252.055 us; speedup 1.0000x reference)
//
#include <hip/hip_runtime.h>
#include <cstddef>

// RNN: h_t = tanh(x_t @ W_ih^T + b_ih + h_{t-1} @ W_hh^T + b_hh), return h_T.
// B=4096, T=512, IN=15, H=20.
//
// R7 post-mortem: pi-pack + u-carry -> 83.4us (391 cyc/step). Issue ~140
// (trans=8cyc calibrated from R5->R7 delta), stall ~250. Work is minimal
// (5 tanh/lane = 320/64 floor); batches exhausted (256 waves x 16 = 4096)
// so wall = 512 * per-step serial time regardless of occupancy. K-merge
// blocked (20+15=35 > 32). Target = scheduling slack around the chain.
//
// R8: latency-ordered step, no math change.
//  - step rotated: XR read -> Xn pack -> cx MFMAs(t+1) -> XR refill issued
//    at TOP, rec MFMAs after -> cx gets a full sub-step of slack, off-chain
//    work sits inside the rec-MFMA/tanh latency window.
//  - Q-MFMA first: uQ0 (Bh word 2 gate) starts exp->rcp earliest.
//  - x addressing SALU-ized: uniform ptr (feature + t*IN) + constant
//    per-lane lane_off -> saddr+voffset loads, scalar tail clamp.
//  - unroll 16.
// Carried from R7 (verified): pi-packed K slots (B slot 8G+i holds u[5G+i],
// i<5), sigma_P(m)=5(m>>2)+(m&3), sigma_Q=5(m>>2)+4; u-carry u=1/(1+2^z)
// with -2 folded into A and +K2*rowsum(Whh) into bias; h = 1-2u epilogue;
// depth-8 XR register pipeline; no LDS anywhere.

typedef float f4 __attribute__((ext_vector_type(4)));
typedef float g4 __attribute__((ext_vector_type(4), aligned(4)));
typedef _Float16 h2 __attribute__((ext_vector_type(2)));
typedef _Float16 v4h __attribute__((ext_vector_type(4)));
typedef _Float16 v8h __attribute__((ext_vector_type(8)));
typedef __fp16 p2 __attribute__((ext_vector_type(2)));

#define TT 512
#define IN 15
#define HD 20
#define NB 16  // batches per wave

__device__ __forceinline__ float fexp2(float x) {
#if __has_builtin(__builtin_amdgcn_exp2f)
  return __builtin_amdgcn_exp2f(x);  // native v_exp_f32
#else
  return exp2f(x);
#endif
}
__device__ __forceinline__ h2 pk2(float a, float b) {
  p2 r = __builtin_amdgcn_cvt_pkrtz(a, b);
  return __builtin_bit_cast(h2, r);
}
__device__ __forceinline__ v4h cat4(h2 a, h2 b) {
  return __builtin_shufflevector(a, b, 0, 1, 2, 3);
}
__device__ __forceinline__ v8h cat8(v4h a, v4h b) {
  return __builtin_shufflevector(a, b, 0, 1, 2, 3, 4, 5, 6, 7);
}

__global__ __launch_bounds__(64) void rnn_mfma(
    const float* __restrict__ feature, const float* __restrict__ W_ih,
    const float* __restrict__ W_hh, const float* __restrict__ b_ih,
    const float* __restrict__ b_hh, float* __restrict__ out, int B) {
  const int l = threadIdx.x;   // 0..63
  const int G = l >> 4;        // k-group 0..3
  const int mf = l & 15;       // A fragment row / B,D batch column
  const int b0 = blockIdx.x * NB;

  const float K2 = 2.8853900817779268f;  // 2*log2(e)

  // --- row assignments (pi-packing) ---------------------------------
  const int jP = 5 * (mf >> 2) + (mf & 3);  // sigma_P(mf), < 20 always
  const int jQ = 5 * (mf >> 2) + 4;         // sigma_Q(mf), < 20 always

  // Recurrence A-fragments: A[m][k=8G+i] = -2*K2*Whh[sigma(m)][5G+i], i<5.
  v8h AhhP, AhhQ;
#pragma unroll
  for (int i = 0; i < 8; ++i) {
    const int k = 5 * G + i;  // h index carried in slot i (valid i<5)
    const float wP = (i < 5) ? -2.f * K2 * W_hh[jP * HD + k] : 0.f;
    const float wQ = (i < 5) ? -2.f * K2 * W_hh[jQ * HD + k] : 0.f;
    AhhP[i] = (_Float16)wP;
    AhhQ[i] = (_Float16)wQ;
  }
  // x-projection A (16x16x16, lane k-window = k0..k0+3). G=3 shifts to
  // k0=11 (avoids 4B OOB at the last row); duplicate k=11 zeroed in G=2.
  const int k0 = (G < 3) ? 4 * G : 11;
  v4h AihP, AihQ;
#pragma unroll
  for (int i = 0; i < 4; ++i) {
    const int k = k0 + i;
    const bool dup = (G == 2 && i == 3);  // k=11 owned by G=3
    AihP[i] = (_Float16)((k < IN && !dup) ? K2 * W_ih[jP * IN + k] : 0.f);
    AihQ[i] = (_Float16)((k < IN && !dup) ? K2 * W_ih[jQ * IN + k] : 0.f);
  }
  // bias as C fragments: D slot (G,r): P -> j=5G+r, Q -> j=5G+4 (all r).
  // Includes +K2*rowsum(Whh[j]) from the h = 1-2u fold.
  f4 biasP, biasQ;
#pragma unroll
  for (int r = 0; r < 4; ++r) {
    const int jp = 5 * G + r, jq = 5 * G + 4;
    float rsP = 0.f, rsQ = 0.f;
#pragma unroll
    for (int k = 0; k < HD; ++k) {
      rsP += W_hh[jp * HD + k];
      rsQ += W_hh[jq * HD + k];
    }
    biasP[r] = K2 * (b_ih[jp] + b_hh[jp] + rsP);
    biasQ[r] = K2 * (b_ih[jq] + b_hh[jq] + rsQ);
  }

  // --- per-lane x source: uniform (feature + t*IN) + constant lane_off.
  // lane_off = b*TT*IN + k0 <= 4095*7680+14 < 2^25: fits the 32-bit
  // voffset of an saddr-form global load; per-step addr math is SALU.
  const int b = min(b0 + mf, B - 1);
  const int lane_off = b * (TT * IN) + k0;
  auto load_t = [&](int t) -> g4 {  // t is wave-uniform (scalar)
    const float* sb = feature + (size_t)t * IN;
    return *(const g4*)(sb + lane_off);
  };

  // depth-8 register pipeline (static indices only under full unroll).
  g4 XR[8];
#pragma unroll
  for (int s = 1; s <= 8; ++s) XR[s & 7] = load_t(s);

  // prologue: cx(0)
  g4 x0 = load_t(0);
  v4h X0 = cat4(pk2(x0.x, x0.y), pk2(x0.z, x0.w));
  f4 cxPc = __builtin_amdgcn_mfma_f32_16x16x16f16(AihP, X0, biasP, 0, 0, 0);
  f4 cxQc = __builtin_amdgcn_mfma_f32_16x16x16f16(AihQ, X0, biasQ, 0, 0, 0);

  // B-fragment carries u; h0 = 0 <=> u0 = 0.5 in live slots (i<5).
  v8h Bh;
#pragma unroll
  for (int i = 0; i < 8; ++i) Bh[i] = (_Float16)((i < 5) ? 0.5f : 0.f);

  float uP[4], uQ0 = 0.5f;  // last u values -> epilogue h = 1-2u
#pragma unroll
  for (int r = 0; r < 4; ++r) uP[r] = 0.5f;

  const h2 zero2 = {(_Float16)0.f, (_Float16)0.f};

  for (int t = 0; t < TT; t += 16) {
#pragma unroll
    for (int u = 0; u < 16; ++u) {
      const int s = (u + 1) & 7;
      // ---- off-chain x machinery for step t+u+1, issued FIRST ----
      g4 xr = XR[s];  // x(t+u+1), loaded 8 steps ago
      v4h Xn = cat4(pk2(xr.x, xr.y), pk2(xr.z, xr.w));
      f4 cxPn = __builtin_amdgcn_mfma_f32_16x16x16f16(AihP, Xn, biasP, 0, 0, 0);
      f4 cxQn = __builtin_amdgcn_mfma_f32_16x16x16f16(AihQ, Xn, biasQ, 0, 0, 0);
      const int tn = t + u + 9;            // scalar; clamp is SALU
      XR[s] = load_t(tn < TT ? tn : TT - 1);
      // ---- recurrence chain for step t+u (Q first: uQ0 gates Bh) ----
      f4 aQ = __builtin_amdgcn_mfma_f32_16x16x32_f16(AhhQ, Bh, cxQc, 0, 0, 0);
      f4 aP = __builtin_amdgcn_mfma_f32_16x16x32_f16(AhhP, Bh, cxPc, 0, 0, 0);
      uQ0 = __builtin_amdgcn_rcpf(1.f + fexp2(aQ[0]));
#pragma unroll
      for (int r = 0; r < 4; ++r)
        uP[r] = __builtin_amdgcn_rcpf(1.f + fexp2(aP[r]));
      Bh = cat8(cat4(pk2(uP[0], uP[1]), pk2(uP[2], uP[3])),
                cat4(pk2(uQ0, 0.f), zero2));
      cxPc = cxPn;  // rotate cx double-buffer (register-renamed by unroll)
      cxQc = cxQn;
    }
  }

  // epilogue: h_T = 1 - 2u. Lane (G,mf): P r -> j=5G+r, Q -> j=5G+4,
  // batch = b0 + mf. All j < 20 by construction.
  const int batch = b0 + mf;
  if (batch < B) {
    float* orow = out + (size_t)batch * HD;
#pragma unroll
    for (int r = 0; r < 4; ++r) orow[5 * G + r] = 1.f - 2.f * uP[r];
    orow[5 * G + 4] = 1.f - 2.f * uQ0;
  }
}

extern "C" void kernel_launch(void* const* d_in, const int* in_sizes, int n_in,
                              void* d_out, int out_size, void* d_ws, size_t ws_size,
                              hipStream_t stream) {
  const float* feature = (const float*)d_in[0];
  const float* W_ih    = (const float*)d_in[1];
  const float* W_hh    = (const float*)d_in[2];
  const float* b_ih    = (const float*)d_in[3];
  const float* b_hh    = (const float*)d_in[4];
  float* out = (float*)d_out;
  const int B = in_sizes[0] / (TT * IN);        // 4096
  const int grid = (B + NB - 1) / NB;           // 16 batches per 64-thread wave
  rnn_mfma<<<grid, 64, 0, stream>>>(feature, W_ih, W_hh, b_ih, b_hh, out, B);
}